// Round 3
// baseline (471.525 us; speedup 1.0000x reference)
//
#include <hip/hip_runtime.h>
#include <math.h>

#define N_NODES 50000
#define N_EDGES 1000000
#define CCH     32
#define ROW     288           // 32 + 96 + 160
#define REC_PAD 64            // float4 units of zero pad after rec (16 records)

// ---------------------------------------------------------------------------
// K1: degree histogram over receivers.
// ---------------------------------------------------------------------------
__global__ __launch_bounds__(256) void hist_kernel(
    const int* __restrict__ edge_index, int* __restrict__ deg)
{
    const int e = blockIdx.x * 256 + threadIdx.x;
    if (e >= N_EDGES) return;
    atomicAdd(&deg[edge_index[N_EDGES + e]], 1);
}

// ---------------------------------------------------------------------------
// K2: fused single-block scan: deg -> offset/cursor (exclusive prefix).
// One 1024-thread block; each thread owns 49 nodes (49*1024 >= 50000).
// Also zeroes the rec padding region (so gather's over-reads are benign:
// snd bits = 0 -> valid node index; values never accumulated since x=0).
// ---------------------------------------------------------------------------
__global__ __launch_bounds__(1024) void scan_fused_kernel(
    const int* __restrict__ deg, int* __restrict__ offset,
    int* __restrict__ cursor, float4* __restrict__ recpad)
{
    __shared__ int s[1024];
    const int t = threadIdx.x;
    const int base = t * 49;
    int sum = 0;
    for (int i = 0; i < 49; ++i) {
        const int g = base + i;
        if (g < N_NODES) sum += deg[g];
    }
    s[t] = sum;
    __syncthreads();
    for (int ofs = 1; ofs < 1024; ofs <<= 1) {
        int w = (t >= ofs) ? s[t - ofs] : 0;
        __syncthreads();
        s[t] += w;
        __syncthreads();
    }
    int run = s[t] - sum;             // exclusive prefix of this chunk
    for (int i = 0; i < 49; ++i) {
        const int g = base + i;
        if (g < N_NODES) {
            offset[g] = run;
            cursor[g] = run;
            run += deg[g];
        }
    }
    if (t < REC_PAD) recpad[t] = make_float4(0.f, 0.f, 0.f, 0.f);
}

// ---------------------------------------------------------------------------
// K3: fused MLP + pack into CSR order (round-0 layout; proven best).
// One 64-B record per edge at its CSR slot:
//   [ h2*inv6 (6) | y0 (1) | y1 (3) | y2 (5) | sender-as-bits (1) ]
// ---------------------------------------------------------------------------
__global__ __launch_bounds__(256) void pack_kernel(
    const float* __restrict__ lenght,     // (E, 8)
    const float* __restrict__ edge_attr,  // (E, 9)
    const int*   __restrict__ edge_index, // (2, E)
    const float* __restrict__ fw0,        // (8, 6)
    const float* __restrict__ fw1,        // (6, 6)
    const float* __restrict__ fw2,        // (6, 6)
    int*         __restrict__ cursor,     // (N)
    float4*      __restrict__ rec)        // (E, 4 x float4)
{
    __shared__ float s_w[120];
    for (int i = threadIdx.x; i < 120; i += 256)
        s_w[i] = (i < 48) ? fw0[i] : (i < 84) ? fw1[i - 48] : fw2[i - 84];
    __syncthreads();
    const float* sw0 = s_w;
    const float* sw1 = s_w + 48;
    const float* sw2 = s_w + 84;

    const int e = blockIdx.x * 256 + threadIdx.x;
    if (e >= N_EDGES) return;

    const float inv8 = 0.35355339059327373f;   // 1/sqrt(8)
    const float inv6 = 0.4082482904638631f;    // 1/sqrt(6)

    float len[8];
    const float4 l0 = ((const float4*)(lenght + (long long)e * 8))[0];
    const float4 l1 = ((const float4*)(lenght + (long long)e * 8))[1];
    len[0]=l0.x; len[1]=l0.y; len[2]=l0.z; len[3]=l0.w;
    len[4]=l1.x; len[5]=l1.y; len[6]=l1.z; len[7]=l1.w;

    float h0[6], h1[6], h2[6];
    #pragma unroll
    for (int j = 0; j < 6; ++j) {
        float a = 0.f;
        #pragma unroll
        for (int k = 0; k < 8; ++k) a += len[k] * sw0[k * 6 + j];
        a *= inv8;
        h0[j] = a / (1.f + __expf(-a));
    }
    #pragma unroll
    for (int j = 0; j < 6; ++j) {
        float a = 0.f;
        #pragma unroll
        for (int k = 0; k < 6; ++k) a += h0[k] * sw1[k * 6 + j];
        a *= inv6;
        h1[j] = a / (1.f + __expf(-a));
    }
    #pragma unroll
    for (int j = 0; j < 6; ++j) {
        float a = 0.f;
        #pragma unroll
        for (int k = 0; k < 6; ++k) a += h1[k] * sw2[k * 6 + j];
        a *= inv6;
        h2[j] = a * inv6 / (1.f + __expf(-a));   // fold final-layer 1/sqrt(6)
    }

    const float* ea = edge_attr + (long long)e * 9;
    float y[9];
    #pragma unroll
    for (int i = 0; i < 9; ++i) y[i] = ea[i];

    const int snd = edge_index[e];
    const int r   = edge_index[N_EDGES + e];
    const int p   = atomicAdd(&cursor[r], 1);

    float4* rp = rec + (long long)p * 4;
    rp[0] = make_float4(h2[0], h2[1], h2[2], h2[3]);
    rp[1] = make_float4(h2[4], h2[5], y[0], y[1]);
    rp[2] = make_float4(y[2], y[3], y[4], y[5]);
    rp[3] = make_float4(y[6], y[7], y[8], __int_as_float(snd));
}

// ---------------------------------------------------------------------------
// K4: gather + message + segment-sum + node linear. One 64-lane wave / node.
// Instruction-economy rewrite:
//  - 4 edges per phase (2 per half-wave), ping-pong A/B register pairs, no
//    register-rotation movs, scalar (wave-uniform) loop count.
//  - No clamps: rec is zero-padded; out-of-range contributions are killed by
//    zeroing x (every message term has x as a factor; neighbor-node records
//    read during overshoot are finite, pad records are zero -> snd=0 valid).
//  - Epilogue: LDS broadcast transpose (b128 reads) instead of 144 bpermutes,
//    then the full 1152-B output row staged in LDS and stored coalesced.
// ---------------------------------------------------------------------------
#define EDGE_ACC(Ra,Rb,Rc,Rd,xx) do {                                          \
    const float w0c_ = Ra.x*f3a[0] + Ra.y*f3a[1] + Ra.z*f3a[2]                 \
                     + Ra.w*f3a[3] + Rb.x*f3a[4] + Rb.y*f3a[5];                \
    const float w1c_ = Ra.x*f3b[0] + Ra.y*f3b[1] + Ra.z*f3b[2]                 \
                     + Ra.w*f3b[3] + Rb.x*f3b[4] + Rb.y*f3b[5];                \
    const float w2c_ = Ra.x*f3c[0] + Ra.y*f3c[1] + Ra.z*f3c[2]                 \
                     + Ra.w*f3c[3] + Rb.x*f3c[4] + Rb.y*f3c[5];                \
    acc[0] += (w0c_ * (xx)) * Rb.z;                                            \
    const float a1_ = w1c_ * (xx);                                             \
    acc[1] += a1_ * Rb.w; acc[2] += a1_ * Rc.x; acc[3] += a1_ * Rc.y;          \
    const float a2_ = w2c_ * (xx);                                             \
    acc[4] += a2_ * Rc.z; acc[5] += a2_ * Rc.w;                                \
    acc[6] += a2_ * Rd.x; acc[7] += a2_ * Rd.y; acc[8] += a2_ * Rd.z;          \
} while (0)

__global__ __launch_bounds__(256) void gather_kernel(
    const float4* __restrict__ rec,          // (E+pad, 4 x float4) CSR order
    const float*  __restrict__ node_features,// (N, 32)
    const int*    __restrict__ offset,       // (N)
    const int*    __restrict__ deg,          // (N)
    const float*  __restrict__ fw3,          // (6, 96)
    const float*  __restrict__ lw0,          // (32, 32)
    const float*  __restrict__ lw1,          // (32, 32)
    const float*  __restrict__ lw2,          // (32, 32)
    float*        __restrict__ out)          // (N, 288)
{
    __shared__ float s_lw0[1024], s_lw1[1024], s_lw2[1024];
    __shared__ float s_m[4][384];            // per-wave: m-stage then row-stage
    {
        const int t = threadIdx.x;
        ((float4*)s_lw0)[t] = ((const float4*)lw0)[t];
        ((float4*)s_lw1)[t] = ((const float4*)lw1)[t];
        ((float4*)s_lw2)[t] = ((const float4*)lw2)[t];
    }
    __syncthreads();

    const int wave = threadIdx.x >> 6;
    const int l    = threadIdx.x & 63;
    const int c    = l & 31;
    const int h    = l >> 5;
    const int node = blockIdx.x * 4 + wave;     // 12500 blocks exact

    float f3a[6], f3b[6], f3c[6];
    #pragma unroll
    for (int k = 0; k < 6; ++k) {
        f3a[k] = fw3[k * 96 + c];
        f3b[k] = fw3[k * 96 + 32 + c];
        f3c[k] = fw3[k * 96 + 64 + c];
    }

    int off = offset[node];
    int dg  = deg[node];
    off = __builtin_amdgcn_readfirstlane(off);   // wave-uniform -> SGPR
    dg  = __builtin_amdgcn_readfirstlane(dg);
    const int nph = (dg + 3) >> 2;               // phases (4 slots each)

    const float4* rb = rec + (size_t)off * 4;    // SGPR base

    float acc[9] = {0.f,0.f,0.f,0.f,0.f,0.f,0.f,0.f,0.f};

    if (nph > 0) {
        // slot pairs: A handles {jA, jA+1}, B handles {jB, jB+1}
        int jA = 2 * h;
        int jB = 2 * h + 4;

        // prologue: load both pairs, x for A pair
        float4 A0 = rb[4*jA+0], A1 = rb[4*jA+1], A2 = rb[4*jA+2], A3 = rb[4*jA+3];
        float4 A4 = rb[4*jA+4], A5 = rb[4*jA+5], A6 = rb[4*jA+6], A7 = rb[4*jA+7];
        float4 B0 = rb[4*jB+0], B1 = rb[4*jB+1], B2 = rb[4*jB+2], B3 = rb[4*jB+3];
        float4 B4 = rb[4*jB+4], B5 = rb[4*jB+5], B6 = rb[4*jB+6], B7 = rb[4*jB+7];
        float xAr0 = node_features[(size_t)__float_as_int(A3.w) * CCH + c];
        float xAr1 = node_features[(size_t)__float_as_int(A7.w) * CCH + c];
        bool  vA0 = (jA < dg), vA1 = (jA + 1 < dg);
        float xBr0 = 0.f, xBr1 = 0.f;
        bool  vB0 = false, vB1 = false;

        int p = 0;
        while (true) {
            // ---- phase A: compute pair A; issue x for B; prefetch next A ----
            {
                const float xA0 = vA0 ? xAr0 : 0.f;
                const float xA1 = vA1 ? xAr1 : 0.f;
                EDGE_ACC(A0, A1, A2, A3, xA0);
                EDGE_ACC(A4, A5, A6, A7, xA1);
                xBr0 = node_features[(size_t)__float_as_int(B3.w) * CCH + c];
                xBr1 = node_features[(size_t)__float_as_int(B7.w) * CCH + c];
                vB0 = (jB < dg); vB1 = (jB + 1 < dg);
                jA += 8;
                A0 = rb[4*jA+0]; A1 = rb[4*jA+1]; A2 = rb[4*jA+2]; A3 = rb[4*jA+3];
                A4 = rb[4*jA+4]; A5 = rb[4*jA+5]; A6 = rb[4*jA+6]; A7 = rb[4*jA+7];
                if (++p == nph) break;
            }
            // ---- phase B: compute pair B; issue x for A; prefetch next B ----
            {
                const float xB0 = vB0 ? xBr0 : 0.f;
                const float xB1 = vB1 ? xBr1 : 0.f;
                EDGE_ACC(B0, B1, B2, B3, xB0);
                EDGE_ACC(B4, B5, B6, B7, xB1);
                xAr0 = node_features[(size_t)__float_as_int(A3.w) * CCH + c];
                xAr1 = node_features[(size_t)__float_as_int(A7.w) * CCH + c];
                vA0 = (jA < dg); vA1 = (jA + 1 < dg);
                jB += 8;
                B0 = rb[4*jB+0]; B1 = rb[4*jB+1]; B2 = rb[4*jB+2]; B3 = rb[4*jB+3];
                B4 = rb[4*jB+4]; B5 = rb[4*jB+5]; B6 = rb[4*jB+6]; B7 = rb[4*jB+7];
                if (++p == nph) break;
            }
        }
    }

    // fold halves: lanes 0..31 hold msg[c][0..8]
    #pragma unroll
    for (int k = 0; k < 9; ++k) acc[k] += __shfl_down(acc[k], 32);

    // stage msg into LDS: s_m[wave][c*12 + k]  (48-B stride -> b128-aligned)
    if (h == 0) {
        float4* mp = (float4*)&s_m[wave][c * 12];
        mp[0] = make_float4(acc[0], acc[1], acc[2], acc[3]);
        mp[1] = make_float4(acc[4], acc[5], acc[6], acc[7]);
        s_m[wave][c * 12 + 8] = acc[8];
    }
    asm volatile("s_waitcnt lgkmcnt(0)" ::: "memory");   // wave-internal fence

    // node linear: broadcast-read m, per-lane lw; halves split the cc loop
    const int d = c;
    float o0 = 0.f;
    float o1[3] = {0.f, 0.f, 0.f};
    float o2[5] = {0.f, 0.f, 0.f, 0.f, 0.f};
    for (int cc = h * 16; cc < h * 16 + 16; ++cc) {
        const float4 ma = *(const float4*)&s_m[wave][cc * 12];
        const float4 mb = *(const float4*)&s_m[wave][cc * 12 + 4];
        const float  m8 = s_m[wave][cc * 12 + 8];
        o0 += ma.x * s_lw0[cc * 32 + d];
        const float w1 = s_lw1[cc * 32 + d];
        o1[0] += ma.y * w1; o1[1] += ma.z * w1; o1[2] += ma.w * w1;
        const float w2 = s_lw2[cc * 32 + d];
        o2[0] += mb.x * w2; o2[1] += mb.y * w2; o2[2] += mb.z * w2;
        o2[3] += mb.w * w2; o2[4] += m8   * w2;
    }

    o0 += __shfl_down(o0, 32);
    #pragma unroll
    for (int i = 0; i < 3; ++i) o1[i] += __shfl_down(o1[i], 32);
    #pragma unroll
    for (int i = 0; i < 5; ++i) o2[i] += __shfl_down(o2[i], 32);

    // stage the 288-float output row in LDS (reuse s_m), store coalesced
    if (h == 0) {
        const float inv32 = 0.17677669529663687f;  // 1/sqrt(32)
        float* rw = &s_m[wave][0];
        rw[d] = o0 * inv32;
        #pragma unroll
        for (int i = 0; i < 3; ++i) rw[32 + d * 3 + i] = o1[i] * inv32;
        #pragma unroll
        for (int i = 0; i < 5; ++i) rw[128 + d * 5 + i] = o2[i] * inv32;
    }
    asm volatile("s_waitcnt lgkmcnt(0)" ::: "memory");

    const float4* rowp = (const float4*)&s_m[wave][0];
    float4* op4 = (float4*)(out + (size_t)node * ROW);
    op4[l] = rowp[l];
    if (l < 8) op4[64 + l] = rowp[64 + l];
}

extern "C" void kernel_launch(void* const* d_in, const int* in_sizes, int n_in,
                              void* d_out, int out_size, void* d_ws, size_t ws_size,
                              hipStream_t stream)
{
    const float* lenght = (const float*)d_in[0];
    const float* nf     = (const float*)d_in[1];
    const float* ea     = (const float*)d_in[2];
    const int*   ei     = (const int*)d_in[3];
    const float* fw0    = (const float*)d_in[4];
    const float* fw1    = (const float*)d_in[5];
    const float* fw2    = (const float*)d_in[6];
    const float* fw3    = (const float*)d_in[7];
    const float* lw0    = (const float*)d_in[8];
    const float* lw1    = (const float*)d_in[9];
    const float* lw2    = (const float*)d_in[10];
    float* out = (float*)d_out;

    // workspace layout
    char* ws = (char*)d_ws;
    float4* rec = (float4*)ws; ws += ((size_t)N_EDGES * 4 + REC_PAD) * sizeof(float4);
    int* deg    = (int*)ws;    ws += (size_t)N_NODES * sizeof(int);
    int* offset = (int*)ws;    ws += (size_t)N_NODES * sizeof(int);
    int* cursor = (int*)ws;    ws += (size_t)N_NODES * sizeof(int);
    float4* recpad = rec + (size_t)N_EDGES * 4;

    hipMemsetAsync(deg, 0, (size_t)N_NODES * sizeof(int), stream);

    const int EB = (N_EDGES + 255) / 256;
    hist_kernel      <<<EB, 256, 0, stream>>>(ei, deg);
    scan_fused_kernel<<<1, 1024, 0, stream>>>(deg, offset, cursor, recpad);
    pack_kernel      <<<EB, 256, 0, stream>>>(lenght, ea, ei, fw0, fw1, fw2, cursor, rec);
    gather_kernel    <<<N_NODES / 4, 256, 0, stream>>>(
        rec, nf, offset, deg, fw3, lw0, lw1, lw2, out);
}

// Round 4
// 355.252 us; speedup vs baseline: 1.3273x; 1.3273x over previous
//
#include <hip/hip_runtime.h>
#include <math.h>

#define N_NODES 50000
#define N_EDGES 1000000
#define CCH     32
#define ROW     288           // 32 + 96 + 160
#define SCAN_BLOCKS 196       // ceil(50000/256)
#define REC_PAD 64            // float4 units of zero pad after rec (16 records)

// ---------------------------------------------------------------------------
// K1: degree histogram over receivers.
// ---------------------------------------------------------------------------
__global__ __launch_bounds__(256) void hist_kernel(
    const int* __restrict__ edge_index, int* __restrict__ deg)
{
    const int e = blockIdx.x * 256 + threadIdx.x;
    if (e >= N_EDGES) return;
    atomicAdd(&deg[edge_index[N_EDGES + e]], 1);
}

// ---------------------------------------------------------------------------
// K2a: per-block scan of deg. Writes local exclusive prefix + block sums.
// ---------------------------------------------------------------------------
__global__ __launch_bounds__(256) void scan_local_kernel(
    const int* __restrict__ deg, int* __restrict__ lexcl, int* __restrict__ blocksum)
{
    __shared__ int s[256];
    const int t = threadIdx.x;
    const int gid = blockIdx.x * 256 + t;
    const int v = (gid < N_NODES) ? deg[gid] : 0;
    s[t] = v;
    __syncthreads();
    for (int ofs = 1; ofs < 256; ofs <<= 1) {
        int w = (t >= ofs) ? s[t - ofs] : 0;
        __syncthreads();
        s[t] += w;
        __syncthreads();
    }
    if (gid < N_NODES) lexcl[gid] = s[t] - v;
    if (t == 255) blocksum[blockIdx.x] = s[255];
}

// ---------------------------------------------------------------------------
// K2b: one tiny block scans the 196 block sums -> exclusive block prefixes.
// ---------------------------------------------------------------------------
__global__ __launch_bounds__(256) void scan_top_kernel(
    const int* __restrict__ blocksum, int* __restrict__ blockpref)
{
    __shared__ int s[256];
    const int t = threadIdx.x;
    const int v = (t < SCAN_BLOCKS) ? blocksum[t] : 0;
    s[t] = v;
    __syncthreads();
    for (int ofs = 1; ofs < 256; ofs <<= 1) {
        int w = (t >= ofs) ? s[t - ofs] : 0;
        __syncthreads();
        s[t] += w;
        __syncthreads();
    }
    if (t < SCAN_BLOCKS) blockpref[t] = s[t] - v;
}

// ---------------------------------------------------------------------------
// K2c: offset[i] = cursor[i] = blockpref[block] + lexcl[i]
// ---------------------------------------------------------------------------
__global__ __launch_bounds__(256) void scan_addback_kernel(
    const int* __restrict__ lexcl, const int* __restrict__ blockpref,
    int* __restrict__ offset, int* __restrict__ cursor)
{
    const int gid = blockIdx.x * 256 + threadIdx.x;
    if (gid >= N_NODES) return;
    const int base = blockpref[blockIdx.x] + lexcl[gid];
    offset[gid] = base;
    cursor[gid] = base;
}

// ---------------------------------------------------------------------------
// K3: fused MLP + pack into CSR order (round-0 layout; proven best).
// One 64-B record per edge at its CSR slot:
//   [ h2*inv6 (6) | y0 (1) | y1 (3) | y2 (5) | sender-as-bits (1) ]
// ---------------------------------------------------------------------------
__global__ __launch_bounds__(256) void pack_kernel(
    const float* __restrict__ lenght,     // (E, 8)
    const float* __restrict__ edge_attr,  // (E, 9)
    const int*   __restrict__ edge_index, // (2, E)
    const float* __restrict__ fw0,        // (8, 6)
    const float* __restrict__ fw1,        // (6, 6)
    const float* __restrict__ fw2,        // (6, 6)
    int*         __restrict__ cursor,     // (N)
    float4*      __restrict__ rec)        // (E, 4 x float4)
{
    __shared__ float s_w[120];
    for (int i = threadIdx.x; i < 120; i += 256)
        s_w[i] = (i < 48) ? fw0[i] : (i < 84) ? fw1[i - 48] : fw2[i - 84];
    __syncthreads();
    const float* sw0 = s_w;
    const float* sw1 = s_w + 48;
    const float* sw2 = s_w + 84;

    const int e = blockIdx.x * 256 + threadIdx.x;
    if (e >= N_EDGES) return;

    const float inv8 = 0.35355339059327373f;   // 1/sqrt(8)
    const float inv6 = 0.4082482904638631f;    // 1/sqrt(6)

    float len[8];
    const float4 l0 = ((const float4*)(lenght + (long long)e * 8))[0];
    const float4 l1 = ((const float4*)(lenght + (long long)e * 8))[1];
    len[0]=l0.x; len[1]=l0.y; len[2]=l0.z; len[3]=l0.w;
    len[4]=l1.x; len[5]=l1.y; len[6]=l1.z; len[7]=l1.w;

    float h0[6], h1[6], h2[6];
    #pragma unroll
    for (int j = 0; j < 6; ++j) {
        float a = 0.f;
        #pragma unroll
        for (int k = 0; k < 8; ++k) a += len[k] * sw0[k * 6 + j];
        a *= inv8;
        h0[j] = a / (1.f + __expf(-a));
    }
    #pragma unroll
    for (int j = 0; j < 6; ++j) {
        float a = 0.f;
        #pragma unroll
        for (int k = 0; k < 6; ++k) a += h0[k] * sw1[k * 6 + j];
        a *= inv6;
        h1[j] = a / (1.f + __expf(-a));
    }
    #pragma unroll
    for (int j = 0; j < 6; ++j) {
        float a = 0.f;
        #pragma unroll
        for (int k = 0; k < 6; ++k) a += h1[k] * sw2[k * 6 + j];
        a *= inv6;
        h2[j] = a * inv6 / (1.f + __expf(-a));   // fold final-layer 1/sqrt(6)
    }

    const float* ea = edge_attr + (long long)e * 9;
    float y[9];
    #pragma unroll
    for (int i = 0; i < 9; ++i) y[i] = ea[i];

    const int snd = edge_index[e];
    const int r   = edge_index[N_EDGES + e];
    const int p   = atomicAdd(&cursor[r], 1);

    float4* rp = rec + (long long)p * 4;
    rp[0] = make_float4(h2[0], h2[1], h2[2], h2[3]);
    rp[1] = make_float4(h2[4], h2[5], y[0], y[1]);
    rp[2] = make_float4(y[2], y[3], y[4], y[5]);
    rp[3] = make_float4(y[6], y[7], y[8], __int_as_float(snd));
}

// ---------------------------------------------------------------------------
// K4: gather + message + segment-sum + node linear. One 64-lane wave / node.
// Instruction-economy loop (proven -~40us in round 3):
//  - 4 edges per phase (2 per half-wave), ping-pong A/B register pairs, no
//    register-rotation movs, scalar (wave-uniform) loop count.
//  - No clamps: rec is zero-padded; out-of-range contributions are killed by
//    zeroing x (every message term has x as a factor; pad records are zero
//    -> snd bits = 0, a valid node index).
//  - Epilogue: LDS broadcast transpose (b128 reads) instead of 144 bpermutes,
//    then the full 1152-B output row staged in LDS and stored coalesced.
// ---------------------------------------------------------------------------
#define EDGE_ACC(Ra,Rb,Rc,Rd,xx) do {                                          \
    const float w0c_ = Ra.x*f3a[0] + Ra.y*f3a[1] + Ra.z*f3a[2]                 \
                     + Ra.w*f3a[3] + Rb.x*f3a[4] + Rb.y*f3a[5];                \
    const float w1c_ = Ra.x*f3b[0] + Ra.y*f3b[1] + Ra.z*f3b[2]                 \
                     + Ra.w*f3b[3] + Rb.x*f3b[4] + Rb.y*f3b[5];                \
    const float w2c_ = Ra.x*f3c[0] + Ra.y*f3c[1] + Ra.z*f3c[2]                 \
                     + Ra.w*f3c[3] + Rb.x*f3c[4] + Rb.y*f3c[5];                \
    acc[0] += (w0c_ * (xx)) * Rb.z;                                            \
    const float a1_ = w1c_ * (xx);                                             \
    acc[1] += a1_ * Rb.w; acc[2] += a1_ * Rc.x; acc[3] += a1_ * Rc.y;          \
    const float a2_ = w2c_ * (xx);                                             \
    acc[4] += a2_ * Rc.z; acc[5] += a2_ * Rc.w;                                \
    acc[6] += a2_ * Rd.x; acc[7] += a2_ * Rd.y; acc[8] += a2_ * Rd.z;          \
} while (0)

__global__ __launch_bounds__(256) void gather_kernel(
    const float4* __restrict__ rec,          // (E+pad, 4 x float4) CSR order
    const float*  __restrict__ node_features,// (N, 32)
    const int*    __restrict__ offset,       // (N)
    const int*    __restrict__ deg,          // (N)
    const float*  __restrict__ fw3,          // (6, 96)
    const float*  __restrict__ lw0,          // (32, 32)
    const float*  __restrict__ lw1,          // (32, 32)
    const float*  __restrict__ lw2,          // (32, 32)
    float*        __restrict__ out)          // (N, 288)
{
    __shared__ float s_lw0[1024], s_lw1[1024], s_lw2[1024];
    __shared__ float s_m[4][384];            // per-wave: m-stage then row-stage
    {
        const int t = threadIdx.x;
        ((float4*)s_lw0)[t] = ((const float4*)lw0)[t];
        ((float4*)s_lw1)[t] = ((const float4*)lw1)[t];
        ((float4*)s_lw2)[t] = ((const float4*)lw2)[t];
    }
    __syncthreads();

    const int wave = threadIdx.x >> 6;
    const int l    = threadIdx.x & 63;
    const int c    = l & 31;
    const int h    = l >> 5;
    const int node = blockIdx.x * 4 + wave;     // 12500 blocks exact

    float f3a[6], f3b[6], f3c[6];
    #pragma unroll
    for (int k = 0; k < 6; ++k) {
        f3a[k] = fw3[k * 96 + c];
        f3b[k] = fw3[k * 96 + 32 + c];
        f3c[k] = fw3[k * 96 + 64 + c];
    }

    int off = offset[node];
    int dg  = deg[node];
    off = __builtin_amdgcn_readfirstlane(off);   // wave-uniform -> SGPR
    dg  = __builtin_amdgcn_readfirstlane(dg);
    const int nph = (dg + 3) >> 2;               // phases (4 slots each)

    const float4* rb = rec + (size_t)off * 4;    // SGPR base

    float acc[9] = {0.f,0.f,0.f,0.f,0.f,0.f,0.f,0.f,0.f};

    if (nph > 0) {
        // slot pairs: A handles {jA, jA+1}, B handles {jB, jB+1}
        int jA = 2 * h;
        int jB = 2 * h + 4;

        // prologue: load both pairs, x for A pair
        float4 A0 = rb[4*jA+0], A1 = rb[4*jA+1], A2 = rb[4*jA+2], A3 = rb[4*jA+3];
        float4 A4 = rb[4*jA+4], A5 = rb[4*jA+5], A6 = rb[4*jA+6], A7 = rb[4*jA+7];
        float4 B0 = rb[4*jB+0], B1 = rb[4*jB+1], B2 = rb[4*jB+2], B3 = rb[4*jB+3];
        float4 B4 = rb[4*jB+4], B5 = rb[4*jB+5], B6 = rb[4*jB+6], B7 = rb[4*jB+7];
        float xAr0 = node_features[(size_t)__float_as_int(A3.w) * CCH + c];
        float xAr1 = node_features[(size_t)__float_as_int(A7.w) * CCH + c];
        bool  vA0 = (jA < dg), vA1 = (jA + 1 < dg);
        float xBr0 = 0.f, xBr1 = 0.f;
        bool  vB0 = false, vB1 = false;

        int p = 0;
        while (true) {
            // ---- phase A: compute pair A; issue x for B; prefetch next A ----
            {
                const float xA0 = vA0 ? xAr0 : 0.f;
                const float xA1 = vA1 ? xAr1 : 0.f;
                EDGE_ACC(A0, A1, A2, A3, xA0);
                EDGE_ACC(A4, A5, A6, A7, xA1);
                xBr0 = node_features[(size_t)__float_as_int(B3.w) * CCH + c];
                xBr1 = node_features[(size_t)__float_as_int(B7.w) * CCH + c];
                vB0 = (jB < dg); vB1 = (jB + 1 < dg);
                jA += 8;
                A0 = rb[4*jA+0]; A1 = rb[4*jA+1]; A2 = rb[4*jA+2]; A3 = rb[4*jA+3];
                A4 = rb[4*jA+4]; A5 = rb[4*jA+5]; A6 = rb[4*jA+6]; A7 = rb[4*jA+7];
                if (++p == nph) break;
            }
            // ---- phase B: compute pair B; issue x for A; prefetch next B ----
            {
                const float xB0 = vB0 ? xBr0 : 0.f;
                const float xB1 = vB1 ? xBr1 : 0.f;
                EDGE_ACC(B0, B1, B2, B3, xB0);
                EDGE_ACC(B4, B5, B6, B7, xB1);
                xAr0 = node_features[(size_t)__float_as_int(A3.w) * CCH + c];
                xAr1 = node_features[(size_t)__float_as_int(A7.w) * CCH + c];
                vA0 = (jA < dg); vA1 = (jA + 1 < dg);
                jB += 8;
                B0 = rb[4*jB+0]; B1 = rb[4*jB+1]; B2 = rb[4*jB+2]; B3 = rb[4*jB+3];
                B4 = rb[4*jB+4]; B5 = rb[4*jB+5]; B6 = rb[4*jB+6]; B7 = rb[4*jB+7];
                if (++p == nph) break;
            }
        }
    }

    // fold halves: lanes 0..31 hold msg[c][0..8]
    #pragma unroll
    for (int k = 0; k < 9; ++k) acc[k] += __shfl_down(acc[k], 32);

    // stage msg into LDS: s_m[wave][c*12 + k]  (48-B stride -> b128-aligned)
    if (h == 0) {
        float4* mp = (float4*)&s_m[wave][c * 12];
        mp[0] = make_float4(acc[0], acc[1], acc[2], acc[3]);
        mp[1] = make_float4(acc[4], acc[5], acc[6], acc[7]);
        s_m[wave][c * 12 + 8] = acc[8];
    }
    asm volatile("s_waitcnt lgkmcnt(0)" ::: "memory");   // wave-internal fence

    // node linear: broadcast-read m, per-lane lw; halves split the cc loop
    const int d = c;
    float o0 = 0.f;
    float o1[3] = {0.f, 0.f, 0.f};
    float o2[5] = {0.f, 0.f, 0.f, 0.f, 0.f};
    for (int cc = h * 16; cc < h * 16 + 16; ++cc) {
        const float4 ma = *(const float4*)&s_m[wave][cc * 12];
        const float4 mb = *(const float4*)&s_m[wave][cc * 12 + 4];
        const float  m8 = s_m[wave][cc * 12 + 8];
        o0 += ma.x * s_lw0[cc * 32 + d];
        const float w1 = s_lw1[cc * 32 + d];
        o1[0] += ma.y * w1; o1[1] += ma.z * w1; o1[2] += ma.w * w1;
        const float w2 = s_lw2[cc * 32 + d];
        o2[0] += mb.x * w2; o2[1] += mb.y * w2; o2[2] += mb.z * w2;
        o2[3] += mb.w * w2; o2[4] += m8   * w2;
    }

    o0 += __shfl_down(o0, 32);
    #pragma unroll
    for (int i = 0; i < 3; ++i) o1[i] += __shfl_down(o1[i], 32);
    #pragma unroll
    for (int i = 0; i < 5; ++i) o2[i] += __shfl_down(o2[i], 32);

    // stage the 288-float output row in LDS (reuse s_m), store coalesced
    if (h == 0) {
        const float inv32 = 0.17677669529663687f;  // 1/sqrt(32)
        float* rw = &s_m[wave][0];
        rw[d] = o0 * inv32;
        #pragma unroll
        for (int i = 0; i < 3; ++i) rw[32 + d * 3 + i] = o1[i] * inv32;
        #pragma unroll
        for (int i = 0; i < 5; ++i) rw[128 + d * 5 + i] = o2[i] * inv32;
    }
    asm volatile("s_waitcnt lgkmcnt(0)" ::: "memory");

    const float4* rowp = (const float4*)&s_m[wave][0];
    float4* op4 = (float4*)(out + (size_t)node * ROW);
    op4[l] = rowp[l];
    if (l < 8) op4[64 + l] = rowp[64 + l];
}

extern "C" void kernel_launch(void* const* d_in, const int* in_sizes, int n_in,
                              void* d_out, int out_size, void* d_ws, size_t ws_size,
                              hipStream_t stream)
{
    const float* lenght = (const float*)d_in[0];
    const float* nf     = (const float*)d_in[1];
    const float* ea     = (const float*)d_in[2];
    const int*   ei     = (const int*)d_in[3];
    const float* fw0    = (const float*)d_in[4];
    const float* fw1    = (const float*)d_in[5];
    const float* fw2    = (const float*)d_in[6];
    const float* fw3    = (const float*)d_in[7];
    const float* lw0    = (const float*)d_in[8];
    const float* lw1    = (const float*)d_in[9];
    const float* lw2    = (const float*)d_in[10];
    float* out = (float*)d_out;

    // workspace layout
    char* ws = (char*)d_ws;
    float4* rec    = (float4*)ws; ws += ((size_t)N_EDGES * 4 + REC_PAD) * sizeof(float4);
    int* deg       = (int*)ws;    ws += (size_t)N_NODES * sizeof(int);
    int* offset    = (int*)ws;    ws += (size_t)N_NODES * sizeof(int);
    int* cursor    = (int*)ws;    ws += (size_t)N_NODES * sizeof(int);
    int* lexcl     = (int*)ws;    ws += (size_t)N_NODES * sizeof(int);
    int* blocksum  = (int*)ws;    ws += (size_t)SCAN_BLOCKS * sizeof(int);
    int* blockpref = (int*)ws;    ws += (size_t)SCAN_BLOCKS * sizeof(int);
    float4* recpad = rec + (size_t)N_EDGES * 4;

    hipMemsetAsync(deg, 0, (size_t)N_NODES * sizeof(int), stream);
    hipMemsetAsync(recpad, 0, (size_t)REC_PAD * sizeof(float4), stream);

    const int EB = (N_EDGES + 255) / 256;
    hist_kernel        <<<EB, 256, 0, stream>>>(ei, deg);
    scan_local_kernel  <<<SCAN_BLOCKS, 256, 0, stream>>>(deg, lexcl, blocksum);
    scan_top_kernel    <<<1, 256, 0, stream>>>(blocksum, blockpref);
    scan_addback_kernel<<<SCAN_BLOCKS, 256, 0, stream>>>(lexcl, blockpref, offset, cursor);
    pack_kernel        <<<EB, 256, 0, stream>>>(lenght, ea, ei, fw0, fw1, fw2, cursor, rec);
    gather_kernel      <<<N_NODES / 4, 256, 0, stream>>>(
        rec, nf, offset, deg, fw3, lw0, lw1, lw2, out);
}

// Round 6
// 353.685 us; speedup vs baseline: 1.3332x; 1.0044x over previous
//
#include <hip/hip_runtime.h>
#include <math.h>

#define N_NODES 50000
#define N_EDGES 1000000
#define CCH     32
#define ROW     288           // 32 + 96 + 160
#define SCAN_BLOCKS 196       // ceil(50000/256)
#define REC_PAD 64            // float4 units of zero pad after rec (16 records)
#define GATHER_BLOCKS 2048    // persistent grid: 8 blocks/CU x 256 CU

// ---------------------------------------------------------------------------
// K1: degree histogram over receivers + intra-receiver rank per edge.
// rank[e] = position of edge e among edges with the same receiver.
// This removes the need for any atomic in pack (p = offset[r] + rank[e]).
// ---------------------------------------------------------------------------
__global__ __launch_bounds__(256) void rank_kernel(
    const int* __restrict__ edge_index, int* __restrict__ deg,
    int* __restrict__ rank)
{
    const int e = blockIdx.x * 256 + threadIdx.x;
    if (e >= N_EDGES) return;
    rank[e] = atomicAdd(&deg[edge_index[N_EDGES + e]], 1);
}

// ---------------------------------------------------------------------------
// K2a: per-block scan of deg. Writes local exclusive prefix + block sums.
// ---------------------------------------------------------------------------
__global__ __launch_bounds__(256) void scan_local_kernel(
    const int* __restrict__ deg, int* __restrict__ lexcl, int* __restrict__ blocksum)
{
    __shared__ int s[256];
    const int t = threadIdx.x;
    const int gid = blockIdx.x * 256 + t;
    const int v = (gid < N_NODES) ? deg[gid] : 0;
    s[t] = v;
    __syncthreads();
    for (int ofs = 1; ofs < 256; ofs <<= 1) {
        int w = (t >= ofs) ? s[t - ofs] : 0;
        __syncthreads();
        s[t] += w;
        __syncthreads();
    }
    if (gid < N_NODES) lexcl[gid] = s[t] - v;
    if (t == 255) blocksum[blockIdx.x] = s[255];
}

// ---------------------------------------------------------------------------
// K2b: one tiny block scans the 196 block sums -> exclusive block prefixes.
// ---------------------------------------------------------------------------
__global__ __launch_bounds__(256) void scan_top_kernel(
    const int* __restrict__ blocksum, int* __restrict__ blockpref)
{
    __shared__ int s[256];
    const int t = threadIdx.x;
    const int v = (t < SCAN_BLOCKS) ? blocksum[t] : 0;
    s[t] = v;
    __syncthreads();
    for (int ofs = 1; ofs < 256; ofs <<= 1) {
        int w = (t >= ofs) ? s[t - ofs] : 0;
        __syncthreads();
        s[t] += w;
        __syncthreads();
    }
    if (t < SCAN_BLOCKS) blockpref[t] = s[t] - v;
}

// ---------------------------------------------------------------------------
// K2c: offset[i] = blockpref[block] + lexcl[i]
// ---------------------------------------------------------------------------
__global__ __launch_bounds__(256) void scan_addback_kernel(
    const int* __restrict__ lexcl, const int* __restrict__ blockpref,
    int* __restrict__ offset)
{
    const int gid = blockIdx.x * 256 + threadIdx.x;
    if (gid >= N_NODES) return;
    offset[gid] = blockpref[blockIdx.x] + lexcl[gid];
}

// ---------------------------------------------------------------------------
// K3: fused MLP + pack into CSR order. NO atomic: slot = offset[r] + rank[e].
// One 64-B record per edge at its CSR slot:
//   [ h2*inv6 (6) | y0 (1) | y1 (3) | y2 (5) | sender-as-bits (1) ]
// ---------------------------------------------------------------------------
__global__ __launch_bounds__(256) void pack_kernel(
    const float* __restrict__ lenght,     // (E, 8)
    const float* __restrict__ edge_attr,  // (E, 9)
    const int*   __restrict__ edge_index, // (2, E)
    const float* __restrict__ fw0,        // (8, 6)
    const float* __restrict__ fw1,        // (6, 6)
    const float* __restrict__ fw2,        // (6, 6)
    const int*   __restrict__ offset,     // (N)
    const int*   __restrict__ rank,       // (E)
    float4*      __restrict__ rec)        // (E, 4 x float4)
{
    __shared__ float s_w[120];
    for (int i = threadIdx.x; i < 120; i += 256)
        s_w[i] = (i < 48) ? fw0[i] : (i < 84) ? fw1[i - 48] : fw2[i - 84];
    __syncthreads();
    const float* sw0 = s_w;
    const float* sw1 = s_w + 48;
    const float* sw2 = s_w + 84;

    const int e = blockIdx.x * 256 + threadIdx.x;
    if (e >= N_EDGES) return;

    const float inv8 = 0.35355339059327373f;   // 1/sqrt(8)
    const float inv6 = 0.4082482904638631f;    // 1/sqrt(6)

    float len[8];
    const float4 l0 = ((const float4*)(lenght + (long long)e * 8))[0];
    const float4 l1 = ((const float4*)(lenght + (long long)e * 8))[1];
    len[0]=l0.x; len[1]=l0.y; len[2]=l0.z; len[3]=l0.w;
    len[4]=l1.x; len[5]=l1.y; len[6]=l1.z; len[7]=l1.w;

    float h0[6], h1[6], h2[6];
    #pragma unroll
    for (int j = 0; j < 6; ++j) {
        float a = 0.f;
        #pragma unroll
        for (int k = 0; k < 8; ++k) a += len[k] * sw0[k * 6 + j];
        a *= inv8;
        h0[j] = a / (1.f + __expf(-a));
    }
    #pragma unroll
    for (int j = 0; j < 6; ++j) {
        float a = 0.f;
        #pragma unroll
        for (int k = 0; k < 6; ++k) a += h0[k] * sw1[k * 6 + j];
        a *= inv6;
        h1[j] = a / (1.f + __expf(-a));
    }
    #pragma unroll
    for (int j = 0; j < 6; ++j) {
        float a = 0.f;
        #pragma unroll
        for (int k = 0; k < 6; ++k) a += h1[k] * sw2[k * 6 + j];
        a *= inv6;
        h2[j] = a * inv6 / (1.f + __expf(-a));   // fold final-layer 1/sqrt(6)
    }

    const float* ea = edge_attr + (long long)e * 9;
    float y[9];
    #pragma unroll
    for (int i = 0; i < 9; ++i) y[i] = ea[i];

    const int snd = edge_index[e];
    const int r   = edge_index[N_EDGES + e];
    const int p   = offset[r] + rank[e];      // no atomic

    float4* rp = rec + (long long)p * 4;
    rp[0] = make_float4(h2[0], h2[1], h2[2], h2[3]);
    rp[1] = make_float4(h2[4], h2[5], y[0], y[1]);
    rp[2] = make_float4(y[2], y[3], y[4], y[5]);
    rp[3] = make_float4(y[6], y[7], y[8], __int_as_float(snd));
}

// ---------------------------------------------------------------------------
// K4: gather + message + segment-sum + node linear. One 64-lane wave / node,
// PERSISTENT GRID (2048 blocks, grid-stride over nodes): waves stay resident
// the whole kernel (fixes the 37% measured occupancy of the 12500-block
// launch), lw-staging and fw3-register loads amortize over ~6 nodes/wave.
// Inner loop unchanged from round 4 (proven): 4 edges/phase ping-pong A/B,
// zero-pad overshoot, LDS-broadcast epilogue, coalesced row store.
// ---------------------------------------------------------------------------
#define EDGE_ACC(Ra,Rb,Rc,Rd,xx) do {                                          \
    const float w0c_ = Ra.x*f3a[0] + Ra.y*f3a[1] + Ra.z*f3a[2]                 \
                     + Ra.w*f3a[3] + Rb.x*f3a[4] + Rb.y*f3a[5];                \
    const float w1c_ = Ra.x*f3b[0] + Ra.y*f3b[1] + Ra.z*f3b[2]                 \
                     + Ra.w*f3b[3] + Rb.x*f3b[4] + Rb.y*f3b[5];                \
    const float w2c_ = Ra.x*f3c[0] + Ra.y*f3c[1] + Ra.z*f3c[2]                 \
                     + Ra.w*f3c[3] + Rb.x*f3c[4] + Rb.y*f3c[5];                \
    acc[0] += (w0c_ * (xx)) * Rb.z;                                            \
    const float a1_ = w1c_ * (xx);                                             \
    acc[1] += a1_ * Rb.w; acc[2] += a1_ * Rc.x; acc[3] += a1_ * Rc.y;          \
    const float a2_ = w2c_ * (xx);                                             \
    acc[4] += a2_ * Rc.z; acc[5] += a2_ * Rc.w;                                \
    acc[6] += a2_ * Rd.x; acc[7] += a2_ * Rd.y; acc[8] += a2_ * Rd.z;          \
} while (0)

__global__ __launch_bounds__(256) void gather_kernel(
    const float4* __restrict__ rec,          // (E+pad, 4 x float4) CSR order
    const float*  __restrict__ node_features,// (N, 32)
    const int*    __restrict__ offset,       // (N)
    const int*    __restrict__ deg,          // (N)
    const float*  __restrict__ fw3,          // (6, 96)
    const float*  __restrict__ lw0,          // (32, 32)
    const float*  __restrict__ lw1,          // (32, 32)
    const float*  __restrict__ lw2,          // (32, 32)
    float*        __restrict__ out)          // (N, 288)
{
    __shared__ float s_lw0[1024], s_lw1[1024], s_lw2[1024];
    __shared__ float s_m[4][384];            // per-wave: m-stage then row-stage
    {
        const int t = threadIdx.x;
        ((float4*)s_lw0)[t] = ((const float4*)lw0)[t];
        ((float4*)s_lw1)[t] = ((const float4*)lw1)[t];
        ((float4*)s_lw2)[t] = ((const float4*)lw2)[t];
    }
    __syncthreads();

    const int wave = threadIdx.x >> 6;
    const int l    = threadIdx.x & 63;
    const int c    = l & 31;
    const int h    = l >> 5;

    float f3a[6], f3b[6], f3c[6];
    #pragma unroll
    for (int k = 0; k < 6; ++k) {
        f3a[k] = fw3[k * 96 + c];
        f3b[k] = fw3[k * 96 + 32 + c];
        f3c[k] = fw3[k * 96 + 64 + c];
    }

    for (int node = blockIdx.x * 4 + wave; node < N_NODES;
         node += GATHER_BLOCKS * 4) {

        int off = offset[node];
        int dg  = deg[node];
        off = __builtin_amdgcn_readfirstlane(off);   // wave-uniform -> SGPR
        dg  = __builtin_amdgcn_readfirstlane(dg);
        const int nph = (dg + 3) >> 2;               // phases (4 slots each)

        const float4* rb = rec + (size_t)off * 4;    // SGPR base

        float acc[9] = {0.f,0.f,0.f,0.f,0.f,0.f,0.f,0.f,0.f};

        if (nph > 0) {
            // slot pairs: A handles {jA, jA+1}, B handles {jB, jB+1}
            int jA = 2 * h;
            int jB = 2 * h + 4;

            // prologue: load both pairs, x for A pair
            float4 A0 = rb[4*jA+0], A1 = rb[4*jA+1], A2 = rb[4*jA+2], A3 = rb[4*jA+3];
            float4 A4 = rb[4*jA+4], A5 = rb[4*jA+5], A6 = rb[4*jA+6], A7 = rb[4*jA+7];
            float4 B0 = rb[4*jB+0], B1 = rb[4*jB+1], B2 = rb[4*jB+2], B3 = rb[4*jB+3];
            float4 B4 = rb[4*jB+4], B5 = rb[4*jB+5], B6 = rb[4*jB+6], B7 = rb[4*jB+7];
            float xAr0 = node_features[(size_t)__float_as_int(A3.w) * CCH + c];
            float xAr1 = node_features[(size_t)__float_as_int(A7.w) * CCH + c];
            bool  vA0 = (jA < dg), vA1 = (jA + 1 < dg);
            float xBr0 = 0.f, xBr1 = 0.f;
            bool  vB0 = false, vB1 = false;

            int p = 0;
            while (true) {
                // ---- phase A: compute pair A; issue x for B; prefetch next A
                {
                    const float xA0 = vA0 ? xAr0 : 0.f;
                    const float xA1 = vA1 ? xAr1 : 0.f;
                    EDGE_ACC(A0, A1, A2, A3, xA0);
                    EDGE_ACC(A4, A5, A6, A7, xA1);
                    xBr0 = node_features[(size_t)__float_as_int(B3.w) * CCH + c];
                    xBr1 = node_features[(size_t)__float_as_int(B7.w) * CCH + c];
                    vB0 = (jB < dg); vB1 = (jB + 1 < dg);
                    jA += 8;
                    A0 = rb[4*jA+0]; A1 = rb[4*jA+1]; A2 = rb[4*jA+2]; A3 = rb[4*jA+3];
                    A4 = rb[4*jA+4]; A5 = rb[4*jA+5]; A6 = rb[4*jA+6]; A7 = rb[4*jA+7];
                    if (++p == nph) break;
                }
                // ---- phase B: compute pair B; issue x for A; prefetch next B
                {
                    const float xB0 = vB0 ? xBr0 : 0.f;
                    const float xB1 = vB1 ? xBr1 : 0.f;
                    EDGE_ACC(B0, B1, B2, B3, xB0);
                    EDGE_ACC(B4, B5, B6, B7, xB1);
                    xAr0 = node_features[(size_t)__float_as_int(A3.w) * CCH + c];
                    xAr1 = node_features[(size_t)__float_as_int(A7.w) * CCH + c];
                    vA0 = (jA < dg); vA1 = (jA + 1 < dg);
                    jB += 8;
                    B0 = rb[4*jB+0]; B1 = rb[4*jB+1]; B2 = rb[4*jB+2]; B3 = rb[4*jB+3];
                    B4 = rb[4*jB+4]; B5 = rb[4*jB+5]; B6 = rb[4*jB+6]; B7 = rb[4*jB+7];
                    if (++p == nph) break;
                }
            }
        }

        // fold halves: lanes 0..31 hold msg[c][0..8]
        #pragma unroll
        for (int k = 0; k < 9; ++k) acc[k] += __shfl_down(acc[k], 32);

        // stage msg into LDS: s_m[wave][c*12 + k]  (48-B stride, b128-aligned)
        if (h == 0) {
            float4* mp = (float4*)&s_m[wave][c * 12];
            mp[0] = make_float4(acc[0], acc[1], acc[2], acc[3]);
            mp[1] = make_float4(acc[4], acc[5], acc[6], acc[7]);
            s_m[wave][c * 12 + 8] = acc[8];
        }
        asm volatile("s_waitcnt lgkmcnt(0)" ::: "memory");   // wave-internal fence

        // node linear: broadcast-read m, per-lane lw; halves split the cc loop
        const int d = c;
        float o0 = 0.f;
        float o1[3] = {0.f, 0.f, 0.f};
        float o2[5] = {0.f, 0.f, 0.f, 0.f, 0.f};
        for (int cc = h * 16; cc < h * 16 + 16; ++cc) {
            const float4 ma = *(const float4*)&s_m[wave][cc * 12];
            const float4 mb = *(const float4*)&s_m[wave][cc * 12 + 4];
            const float  m8 = s_m[wave][cc * 12 + 8];
            o0 += ma.x * s_lw0[cc * 32 + d];
            const float w1 = s_lw1[cc * 32 + d];
            o1[0] += ma.y * w1; o1[1] += ma.z * w1; o1[2] += ma.w * w1;
            const float w2 = s_lw2[cc * 32 + d];
            o2[0] += mb.x * w2; o2[1] += mb.y * w2; o2[2] += mb.z * w2;
            o2[3] += mb.w * w2; o2[4] += m8   * w2;
        }

        o0 += __shfl_down(o0, 32);
        #pragma unroll
        for (int i = 0; i < 3; ++i) o1[i] += __shfl_down(o1[i], 32);
        #pragma unroll
        for (int i = 0; i < 5; ++i) o2[i] += __shfl_down(o2[i], 32);

        // stage the 288-float output row in LDS (reuse s_m), store coalesced
        if (h == 0) {
            const float inv32 = 0.17677669529663687f;  // 1/sqrt(32)
            float* rw = &s_m[wave][0];
            rw[d] = o0 * inv32;
            #pragma unroll
            for (int i = 0; i < 3; ++i) rw[32 + d * 3 + i] = o1[i] * inv32;
            #pragma unroll
            for (int i = 0; i < 5; ++i) rw[128 + d * 5 + i] = o2[i] * inv32;
        }
        asm volatile("s_waitcnt lgkmcnt(0)" ::: "memory");

        const float4* rowp = (const float4*)&s_m[wave][0];
        float4* op4 = (float4*)(out + (size_t)node * ROW);
        op4[l] = rowp[l];
        if (l < 8) op4[64 + l] = rowp[64 + l];
    }
}

extern "C" void kernel_launch(void* const* d_in, const int* in_sizes, int n_in,
                              void* d_out, int out_size, void* d_ws, size_t ws_size,
                              hipStream_t stream)
{
    const float* lenght = (const float*)d_in[0];
    const float* nf     = (const float*)d_in[1];
    const float* ea     = (const float*)d_in[2];
    const int*   ei     = (const int*)d_in[3];
    const float* fw0    = (const float*)d_in[4];
    const float* fw1    = (const float*)d_in[5];
    const float* fw2    = (const float*)d_in[6];
    const float* fw3    = (const float*)d_in[7];
    const float* lw0    = (const float*)d_in[8];
    const float* lw1    = (const float*)d_in[9];
    const float* lw2    = (const float*)d_in[10];
    float* out = (float*)d_out;

    // workspace layout
    char* ws = (char*)d_ws;
    float4* rec    = (float4*)ws; ws += ((size_t)N_EDGES * 4 + REC_PAD) * sizeof(float4);
    int* rank      = (int*)ws;    ws += (size_t)N_EDGES * sizeof(int);
    int* deg       = (int*)ws;    ws += (size_t)N_NODES * sizeof(int);
    int* offset    = (int*)ws;    ws += (size_t)N_NODES * sizeof(int);
    int* lexcl     = (int*)ws;    ws += (size_t)N_NODES * sizeof(int);
    int* blocksum  = (int*)ws;    ws += (size_t)SCAN_BLOCKS * sizeof(int);
    int* blockpref = (int*)ws;    ws += (size_t)SCAN_BLOCKS * sizeof(int);
    float4* recpad = rec + (size_t)N_EDGES * 4;

    hipMemsetAsync(deg, 0, (size_t)N_NODES * sizeof(int), stream);
    hipMemsetAsync(recpad, 0, (size_t)REC_PAD * sizeof(float4), stream);

    const int EB = (N_EDGES + 255) / 256;
    rank_kernel        <<<EB, 256, 0, stream>>>(ei, deg, rank);
    scan_local_kernel  <<<SCAN_BLOCKS, 256, 0, stream>>>(deg, lexcl, blocksum);
    scan_top_kernel    <<<1, 256, 0, stream>>>(blocksum, blockpref);
    scan_addback_kernel<<<SCAN_BLOCKS, 256, 0, stream>>>(lexcl, blockpref, offset);
    pack_kernel        <<<EB, 256, 0, stream>>>(lenght, ea, ei, fw0, fw1, fw2,
                                                offset, rank, rec);
    gather_kernel      <<<GATHER_BLOCKS, 256, 0, stream>>>(
        rec, nf, offset, deg, fw3, lw0, lw1, lw2, out);
}

// Round 7
// 341.150 us; speedup vs baseline: 1.3822x; 1.0367x over previous
//
#include <hip/hip_runtime.h>
#include <math.h>

#define N_NODES 50000
#define N_EDGES 1000000
#define CCH     32
#define ROW     288           // 32 + 96 + 160
#define SCAN_BLOCKS 196       // ceil(50000/256)
#define REC_PAD 64            // float4 units of zero pad after rec (16 records)

// ---------------------------------------------------------------------------
// K1: degree histogram over receivers + intra-receiver rank per edge.
// rank[e] = position of edge e among edges with the same receiver.
// Removes the returning atomic from pack (p = offset[r] + rank[e]).
// ---------------------------------------------------------------------------
__global__ __launch_bounds__(256) void rank_kernel(
    const int* __restrict__ edge_index, int* __restrict__ deg,
    int* __restrict__ rank)
{
    const int e = blockIdx.x * 256 + threadIdx.x;
    if (e >= N_EDGES) return;
    rank[e] = atomicAdd(&deg[edge_index[N_EDGES + e]], 1);
}

// ---------------------------------------------------------------------------
// K2a: per-block scan of deg. Writes local exclusive prefix + block sums.
// ---------------------------------------------------------------------------
__global__ __launch_bounds__(256) void scan_local_kernel(
    const int* __restrict__ deg, int* __restrict__ lexcl, int* __restrict__ blocksum)
{
    __shared__ int s[256];
    const int t = threadIdx.x;
    const int gid = blockIdx.x * 256 + t;
    const int v = (gid < N_NODES) ? deg[gid] : 0;
    s[t] = v;
    __syncthreads();
    for (int ofs = 1; ofs < 256; ofs <<= 1) {
        int w = (t >= ofs) ? s[t - ofs] : 0;
        __syncthreads();
        s[t] += w;
        __syncthreads();
    }
    if (gid < N_NODES) lexcl[gid] = s[t] - v;
    if (t == 255) blocksum[blockIdx.x] = s[255];
}

// ---------------------------------------------------------------------------
// K2b: one tiny block scans the 196 block sums -> exclusive block prefixes.
// ---------------------------------------------------------------------------
__global__ __launch_bounds__(256) void scan_top_kernel(
    const int* __restrict__ blocksum, int* __restrict__ blockpref)
{
    __shared__ int s[256];
    const int t = threadIdx.x;
    const int v = (t < SCAN_BLOCKS) ? blocksum[t] : 0;
    s[t] = v;
    __syncthreads();
    for (int ofs = 1; ofs < 256; ofs <<= 1) {
        int w = (t >= ofs) ? s[t - ofs] : 0;
        __syncthreads();
        s[t] += w;
        __syncthreads();
    }
    if (t < SCAN_BLOCKS) blockpref[t] = s[t] - v;
}

// ---------------------------------------------------------------------------
// K2c: offset[i] = blockpref[block] + lexcl[i]
// ---------------------------------------------------------------------------
__global__ __launch_bounds__(256) void scan_addback_kernel(
    const int* __restrict__ lexcl, const int* __restrict__ blockpref,
    int* __restrict__ offset)
{
    const int gid = blockIdx.x * 256 + threadIdx.x;
    if (gid >= N_NODES) return;
    offset[gid] = blockpref[blockIdx.x] + lexcl[gid];
}

// ---------------------------------------------------------------------------
// K3: fused MLP + pack into CSR order. NO atomic: slot = offset[r] + rank[e].
// edge_attr is staged through LDS: the block's 256x9 floats are read with
// fully sequential coalesced loads (9 insts/thread, stride 256), then each
// thread reads its 9 from LDS (stride 9, gcd(9,32)=1 -> conflict-free).
// One 64-B record per edge at its CSR slot:
//   [ h2*inv6 (6) | y0 (1) | y1 (3) | y2 (5) | sender-as-bits (1) ]
// ---------------------------------------------------------------------------
__global__ __launch_bounds__(256) void pack_kernel(
    const float* __restrict__ lenght,     // (E, 8)
    const float* __restrict__ edge_attr,  // (E, 9)
    const int*   __restrict__ edge_index, // (2, E)
    const float* __restrict__ fw0,        // (8, 6)
    const float* __restrict__ fw1,        // (6, 6)
    const float* __restrict__ fw2,        // (6, 6)
    const int*   __restrict__ offset,     // (N)
    const int*   __restrict__ rank,       // (E)
    float4*      __restrict__ rec)        // (E, 4 x float4)
{
    __shared__ float s_w[120];
    __shared__ float s_ea[256 * 9];
    for (int i = threadIdx.x; i < 120; i += 256)
        s_w[i] = (i < 48) ? fw0[i] : (i < 84) ? fw1[i - 48] : fw2[i - 84];
    {
        const int base_dw = blockIdx.x * (256 * 9);
        #pragma unroll
        for (int k = 0; k < 9; ++k) {
            const int i = k * 256 + threadIdx.x;
            const int g = base_dw + i;
            if (g < 9 * N_EDGES) s_ea[i] = edge_attr[g];
        }
    }
    __syncthreads();
    const float* sw0 = s_w;
    const float* sw1 = s_w + 48;
    const float* sw2 = s_w + 84;

    const int e = blockIdx.x * 256 + threadIdx.x;
    if (e >= N_EDGES) return;

    const float inv8 = 0.35355339059327373f;   // 1/sqrt(8)
    const float inv6 = 0.4082482904638631f;    // 1/sqrt(6)

    float len[8];
    const float4 l0 = ((const float4*)(lenght + (long long)e * 8))[0];
    const float4 l1 = ((const float4*)(lenght + (long long)e * 8))[1];
    len[0]=l0.x; len[1]=l0.y; len[2]=l0.z; len[3]=l0.w;
    len[4]=l1.x; len[5]=l1.y; len[6]=l1.z; len[7]=l1.w;

    float h0[6], h1[6], h2[6];
    #pragma unroll
    for (int j = 0; j < 6; ++j) {
        float a = 0.f;
        #pragma unroll
        for (int k = 0; k < 8; ++k) a += len[k] * sw0[k * 6 + j];
        a *= inv8;
        h0[j] = a / (1.f + __expf(-a));
    }
    #pragma unroll
    for (int j = 0; j < 6; ++j) {
        float a = 0.f;
        #pragma unroll
        for (int k = 0; k < 6; ++k) a += h0[k] * sw1[k * 6 + j];
        a *= inv6;
        h1[j] = a / (1.f + __expf(-a));
    }
    #pragma unroll
    for (int j = 0; j < 6; ++j) {
        float a = 0.f;
        #pragma unroll
        for (int k = 0; k < 6; ++k) a += h1[k] * sw2[k * 6 + j];
        a *= inv6;
        h2[j] = a * inv6 / (1.f + __expf(-a));   // fold final-layer 1/sqrt(6)
    }

    const float* ea = s_ea + threadIdx.x * 9;
    float y[9];
    #pragma unroll
    for (int i = 0; i < 9; ++i) y[i] = ea[i];

    const int snd = edge_index[e];
    const int r   = edge_index[N_EDGES + e];
    const int p   = offset[r] + rank[e];      // no atomic

    float4* rp = rec + (long long)p * 4;
    rp[0] = make_float4(h2[0], h2[1], h2[2], h2[3]);
    rp[1] = make_float4(h2[4], h2[5], y[0], y[1]);
    rp[2] = make_float4(y[2], y[3], y[4], y[5]);
    rp[3] = make_float4(y[6], y[7], y[8], __int_as_float(snd));
}

// ---------------------------------------------------------------------------
// K4: gather + message + segment-sum + node linear. One 64-lane wave / node,
// 12500 blocks (4 nodes/block) — the proven-best configuration (121 us,
// VGPR 52). Persistent-grid variant measured WORSE (VGPR 84 crosses the
// 64-VGPR occupancy boundary). Inner loop: 4 edges/phase ping-pong A/B,
// zero-pad overshoot, LDS-broadcast epilogue, coalesced row store.
// ---------------------------------------------------------------------------
#define EDGE_ACC(Ra,Rb,Rc,Rd,xx) do {                                          \
    const float w0c_ = Ra.x*f3a[0] + Ra.y*f3a[1] + Ra.z*f3a[2]                 \
                     + Ra.w*f3a[3] + Rb.x*f3a[4] + Rb.y*f3a[5];                \
    const float w1c_ = Ra.x*f3b[0] + Ra.y*f3b[1] + Ra.z*f3b[2]                 \
                     + Ra.w*f3b[3] + Rb.x*f3b[4] + Rb.y*f3b[5];                \
    const float w2c_ = Ra.x*f3c[0] + Ra.y*f3c[1] + Ra.z*f3c[2]                 \
                     + Ra.w*f3c[3] + Rb.x*f3c[4] + Rb.y*f3c[5];                \
    acc[0] += (w0c_ * (xx)) * Rb.z;                                            \
    const float a1_ = w1c_ * (xx);                                             \
    acc[1] += a1_ * Rb.w; acc[2] += a1_ * Rc.x; acc[3] += a1_ * Rc.y;          \
    const float a2_ = w2c_ * (xx);                                             \
    acc[4] += a2_ * Rc.z; acc[5] += a2_ * Rc.w;                                \
    acc[6] += a2_ * Rd.x; acc[7] += a2_ * Rd.y; acc[8] += a2_ * Rd.z;          \
} while (0)

__global__ __launch_bounds__(256) void gather_kernel(
    const float4* __restrict__ rec,          // (E+pad, 4 x float4) CSR order
    const float*  __restrict__ node_features,// (N, 32)
    const int*    __restrict__ offset,       // (N)
    const int*    __restrict__ deg,          // (N)
    const float*  __restrict__ fw3,          // (6, 96)
    const float*  __restrict__ lw0,          // (32, 32)
    const float*  __restrict__ lw1,          // (32, 32)
    const float*  __restrict__ lw2,          // (32, 32)
    float*        __restrict__ out)          // (N, 288)
{
    __shared__ float s_lw0[1024], s_lw1[1024], s_lw2[1024];
    __shared__ float s_m[4][384];            // per-wave: m-stage then row-stage
    {
        const int t = threadIdx.x;
        ((float4*)s_lw0)[t] = ((const float4*)lw0)[t];
        ((float4*)s_lw1)[t] = ((const float4*)lw1)[t];
        ((float4*)s_lw2)[t] = ((const float4*)lw2)[t];
    }
    __syncthreads();

    const int wave = threadIdx.x >> 6;
    const int l    = threadIdx.x & 63;
    const int c    = l & 31;
    const int h    = l >> 5;
    const int node = blockIdx.x * 4 + wave;     // 12500 blocks exact

    float f3a[6], f3b[6], f3c[6];
    #pragma unroll
    for (int k = 0; k < 6; ++k) {
        f3a[k] = fw3[k * 96 + c];
        f3b[k] = fw3[k * 96 + 32 + c];
        f3c[k] = fw3[k * 96 + 64 + c];
    }

    int off = offset[node];
    int dg  = deg[node];
    off = __builtin_amdgcn_readfirstlane(off);   // wave-uniform -> SGPR
    dg  = __builtin_amdgcn_readfirstlane(dg);
    const int nph = (dg + 3) >> 2;               // phases (4 slots each)

    const float4* rb = rec + (size_t)off * 4;    // SGPR base

    float acc[9] = {0.f,0.f,0.f,0.f,0.f,0.f,0.f,0.f,0.f};

    if (nph > 0) {
        // slot pairs: A handles {jA, jA+1}, B handles {jB, jB+1}
        int jA = 2 * h;
        int jB = 2 * h + 4;

        // prologue: load both pairs, x for A pair
        float4 A0 = rb[4*jA+0], A1 = rb[4*jA+1], A2 = rb[4*jA+2], A3 = rb[4*jA+3];
        float4 A4 = rb[4*jA+4], A5 = rb[4*jA+5], A6 = rb[4*jA+6], A7 = rb[4*jA+7];
        float4 B0 = rb[4*jB+0], B1 = rb[4*jB+1], B2 = rb[4*jB+2], B3 = rb[4*jB+3];
        float4 B4 = rb[4*jB+4], B5 = rb[4*jB+5], B6 = rb[4*jB+6], B7 = rb[4*jB+7];
        float xAr0 = node_features[(size_t)__float_as_int(A3.w) * CCH + c];
        float xAr1 = node_features[(size_t)__float_as_int(A7.w) * CCH + c];
        bool  vA0 = (jA < dg), vA1 = (jA + 1 < dg);
        float xBr0 = 0.f, xBr1 = 0.f;
        bool  vB0 = false, vB1 = false;

        int p = 0;
        while (true) {
            // ---- phase A: compute pair A; issue x for B; prefetch next A ----
            {
                const float xA0 = vA0 ? xAr0 : 0.f;
                const float xA1 = vA1 ? xAr1 : 0.f;
                EDGE_ACC(A0, A1, A2, A3, xA0);
                EDGE_ACC(A4, A5, A6, A7, xA1);
                xBr0 = node_features[(size_t)__float_as_int(B3.w) * CCH + c];
                xBr1 = node_features[(size_t)__float_as_int(B7.w) * CCH + c];
                vB0 = (jB < dg); vB1 = (jB + 1 < dg);
                jA += 8;
                A0 = rb[4*jA+0]; A1 = rb[4*jA+1]; A2 = rb[4*jA+2]; A3 = rb[4*jA+3];
                A4 = rb[4*jA+4]; A5 = rb[4*jA+5]; A6 = rb[4*jA+6]; A7 = rb[4*jA+7];
                if (++p == nph) break;
            }
            // ---- phase B: compute pair B; issue x for A; prefetch next B ----
            {
                const float xB0 = vB0 ? xBr0 : 0.f;
                const float xB1 = vB1 ? xBr1 : 0.f;
                EDGE_ACC(B0, B1, B2, B3, xB0);
                EDGE_ACC(B4, B5, B6, B7, xB1);
                xAr0 = node_features[(size_t)__float_as_int(A3.w) * CCH + c];
                xAr1 = node_features[(size_t)__float_as_int(A7.w) * CCH + c];
                vA0 = (jA < dg); vA1 = (jA + 1 < dg);
                jB += 8;
                B0 = rb[4*jB+0]; B1 = rb[4*jB+1]; B2 = rb[4*jB+2]; B3 = rb[4*jB+3];
                B4 = rb[4*jB+4]; B5 = rb[4*jB+5]; B6 = rb[4*jB+6]; B7 = rb[4*jB+7];
                if (++p == nph) break;
            }
        }
    }

    // fold halves: lanes 0..31 hold msg[c][0..8]
    #pragma unroll
    for (int k = 0; k < 9; ++k) acc[k] += __shfl_down(acc[k], 32);

    // stage msg into LDS: s_m[wave][c*12 + k]  (48-B stride, b128-aligned)
    if (h == 0) {
        float4* mp = (float4*)&s_m[wave][c * 12];
        mp[0] = make_float4(acc[0], acc[1], acc[2], acc[3]);
        mp[1] = make_float4(acc[4], acc[5], acc[6], acc[7]);
        s_m[wave][c * 12 + 8] = acc[8];
    }
    asm volatile("s_waitcnt lgkmcnt(0)" ::: "memory");   // wave-internal fence

    // node linear: broadcast-read m, per-lane lw; halves split the cc loop
    const int d = c;
    float o0 = 0.f;
    float o1[3] = {0.f, 0.f, 0.f};
    float o2[5] = {0.f, 0.f, 0.f, 0.f, 0.f};
    for (int cc = h * 16; cc < h * 16 + 16; ++cc) {
        const float4 ma = *(const float4*)&s_m[wave][cc * 12];
        const float4 mb = *(const float4*)&s_m[wave][cc * 12 + 4];
        const float  m8 = s_m[wave][cc * 12 + 8];
        o0 += ma.x * s_lw0[cc * 32 + d];
        const float w1 = s_lw1[cc * 32 + d];
        o1[0] += ma.y * w1; o1[1] += ma.z * w1; o1[2] += ma.w * w1;
        const float w2 = s_lw2[cc * 32 + d];
        o2[0] += mb.x * w2; o2[1] += mb.y * w2; o2[2] += mb.z * w2;
        o2[3] += mb.w * w2; o2[4] += m8   * w2;
    }

    o0 += __shfl_down(o0, 32);
    #pragma unroll
    for (int i = 0; i < 3; ++i) o1[i] += __shfl_down(o1[i], 32);
    #pragma unroll
    for (int i = 0; i < 5; ++i) o2[i] += __shfl_down(o2[i], 32);

    // stage the 288-float output row in LDS (reuse s_m), store coalesced
    if (h == 0) {
        const float inv32 = 0.17677669529663687f;  // 1/sqrt(32)
        float* rw = &s_m[wave][0];
        rw[d] = o0 * inv32;
        #pragma unroll
        for (int i = 0; i < 3; ++i) rw[32 + d * 3 + i] = o1[i] * inv32;
        #pragma unroll
        for (int i = 0; i < 5; ++i) rw[128 + d * 5 + i] = o2[i] * inv32;
    }
    asm volatile("s_waitcnt lgkmcnt(0)" ::: "memory");

    const float4* rowp = (const float4*)&s_m[wave][0];
    float4* op4 = (float4*)(out + (size_t)node * ROW);
    op4[l] = rowp[l];
    if (l < 8) op4[64 + l] = rowp[64 + l];
}

extern "C" void kernel_launch(void* const* d_in, const int* in_sizes, int n_in,
                              void* d_out, int out_size, void* d_ws, size_t ws_size,
                              hipStream_t stream)
{
    const float* lenght = (const float*)d_in[0];
    const float* nf     = (const float*)d_in[1];
    const float* ea     = (const float*)d_in[2];
    const int*   ei     = (const int*)d_in[3];
    const float* fw0    = (const float*)d_in[4];
    const float* fw1    = (const float*)d_in[5];
    const float* fw2    = (const float*)d_in[6];
    const float* fw3    = (const float*)d_in[7];
    const float* lw0    = (const float*)d_in[8];
    const float* lw1    = (const float*)d_in[9];
    const float* lw2    = (const float*)d_in[10];
    float* out = (float*)d_out;

    // workspace layout
    char* ws = (char*)d_ws;
    float4* rec    = (float4*)ws; ws += ((size_t)N_EDGES * 4 + REC_PAD) * sizeof(float4);
    int* rank      = (int*)ws;    ws += (size_t)N_EDGES * sizeof(int);
    int* deg       = (int*)ws;    ws += (size_t)N_NODES * sizeof(int);
    int* offset    = (int*)ws;    ws += (size_t)N_NODES * sizeof(int);
    int* lexcl     = (int*)ws;    ws += (size_t)N_NODES * sizeof(int);
    int* blocksum  = (int*)ws;    ws += (size_t)SCAN_BLOCKS * sizeof(int);
    int* blockpref = (int*)ws;    ws += (size_t)SCAN_BLOCKS * sizeof(int);
    float4* recpad = rec + (size_t)N_EDGES * 4;

    hipMemsetAsync(deg, 0, (size_t)N_NODES * sizeof(int), stream);
    hipMemsetAsync(recpad, 0, (size_t)REC_PAD * sizeof(float4), stream);

    const int EB = (N_EDGES + 255) / 256;
    rank_kernel        <<<EB, 256, 0, stream>>>(ei, deg, rank);
    scan_local_kernel  <<<SCAN_BLOCKS, 256, 0, stream>>>(deg, lexcl, blocksum);
    scan_top_kernel    <<<1, 256, 0, stream>>>(blocksum, blockpref);
    scan_addback_kernel<<<SCAN_BLOCKS, 256, 0, stream>>>(lexcl, blockpref, offset);
    pack_kernel        <<<EB, 256, 0, stream>>>(lenght, ea, ei, fw0, fw1, fw2,
                                                offset, rank, rec);
    gather_kernel      <<<N_NODES / 4, 256, 0, stream>>>(
        rec, nf, offset, deg, fw3, lw0, lw1, lw2, out);
}

// Round 8
// 337.038 us; speedup vs baseline: 1.3990x; 1.0122x over previous
//
#include <hip/hip_runtime.h>
#include <math.h>

#define N_NODES 50000
#define N_EDGES 1000000
#define CCH     32
#define ROW     288           // 32 + 96 + 160
#define SCAN_BLOCKS 196       // ceil(50000/256)
#define REC_PAD 64            // float4 units of zero pad after rec (16 records)

// ---------------------------------------------------------------------------
// K1: degree histogram over receivers + intra-receiver rank per edge.
// rank[e] = position of edge e among edges with the same receiver.
// Removes the returning atomic from pack (p = offset[r] + rank[e]).
// ---------------------------------------------------------------------------
__global__ __launch_bounds__(256) void rank_kernel(
    const int* __restrict__ edge_index, int* __restrict__ deg,
    int* __restrict__ rank)
{
    const int e = blockIdx.x * 256 + threadIdx.x;
    if (e >= N_EDGES) return;
    rank[e] = atomicAdd(&deg[edge_index[N_EDGES + e]], 1);
}

// ---------------------------------------------------------------------------
// K2a: per-block scan of deg. Writes local exclusive prefix + block sums.
// ---------------------------------------------------------------------------
__global__ __launch_bounds__(256) void scan_local_kernel(
    const int* __restrict__ deg, int* __restrict__ lexcl, int* __restrict__ blocksum)
{
    __shared__ int s[256];
    const int t = threadIdx.x;
    const int gid = blockIdx.x * 256 + t;
    const int v = (gid < N_NODES) ? deg[gid] : 0;
    s[t] = v;
    __syncthreads();
    for (int ofs = 1; ofs < 256; ofs <<= 1) {
        int w = (t >= ofs) ? s[t - ofs] : 0;
        __syncthreads();
        s[t] += w;
        __syncthreads();
    }
    if (gid < N_NODES) lexcl[gid] = s[t] - v;
    if (t == 255) blocksum[blockIdx.x] = s[255];
}

// ---------------------------------------------------------------------------
// K2b: one tiny block scans the 196 block sums -> exclusive block prefixes.
// ---------------------------------------------------------------------------
__global__ __launch_bounds__(256) void scan_top_kernel(
    const int* __restrict__ blocksum, int* __restrict__ blockpref)
{
    __shared__ int s[256];
    const int t = threadIdx.x;
    const int v = (t < SCAN_BLOCKS) ? blocksum[t] : 0;
    s[t] = v;
    __syncthreads();
    for (int ofs = 1; ofs < 256; ofs <<= 1) {
        int w = (t >= ofs) ? s[t - ofs] : 0;
        __syncthreads();
        s[t] += w;
        __syncthreads();
    }
    if (t < SCAN_BLOCKS) blockpref[t] = s[t] - v;
}

// ---------------------------------------------------------------------------
// K2c: offset[i] = blockpref[block] + lexcl[i]
// ---------------------------------------------------------------------------
__global__ __launch_bounds__(256) void scan_addback_kernel(
    const int* __restrict__ lexcl, const int* __restrict__ blockpref,
    int* __restrict__ offset)
{
    const int gid = blockIdx.x * 256 + threadIdx.x;
    if (gid >= N_NODES) return;
    offset[gid] = blockpref[blockIdx.x] + lexcl[gid];
}

// ---------------------------------------------------------------------------
// K3: fused MLP + pack into CSR order. NO atomic: slot = offset[r] + rank[e].
// edge_attr staged through LDS (sequential coalesced loads; stride-9 LDS
// reads are conflict-free since gcd(9,32)=1).
// One 64-B record per edge at its CSR slot:
//   [ h2*inv6 (6) | y0 (1) | y1 (3) | y2 (5) | sender-as-bits (1) ]
// ---------------------------------------------------------------------------
__global__ __launch_bounds__(256) void pack_kernel(
    const float* __restrict__ lenght,     // (E, 8)
    const float* __restrict__ edge_attr,  // (E, 9)
    const int*   __restrict__ edge_index, // (2, E)
    const float* __restrict__ fw0,        // (8, 6)
    const float* __restrict__ fw1,        // (6, 6)
    const float* __restrict__ fw2,        // (6, 6)
    const int*   __restrict__ offset,     // (N)
    const int*   __restrict__ rank,       // (E)
    float4*      __restrict__ rec)        // (E, 4 x float4)
{
    __shared__ float s_w[120];
    __shared__ float s_ea[256 * 9];
    for (int i = threadIdx.x; i < 120; i += 256)
        s_w[i] = (i < 48) ? fw0[i] : (i < 84) ? fw1[i - 48] : fw2[i - 84];
    {
        const int base_dw = blockIdx.x * (256 * 9);
        #pragma unroll
        for (int k = 0; k < 9; ++k) {
            const int i = k * 256 + threadIdx.x;
            const int g = base_dw + i;
            if (g < 9 * N_EDGES) s_ea[i] = edge_attr[g];
        }
    }
    __syncthreads();
    const float* sw0 = s_w;
    const float* sw1 = s_w + 48;
    const float* sw2 = s_w + 84;

    const int e = blockIdx.x * 256 + threadIdx.x;
    if (e >= N_EDGES) return;

    const float inv8 = 0.35355339059327373f;   // 1/sqrt(8)
    const float inv6 = 0.4082482904638631f;    // 1/sqrt(6)

    float len[8];
    const float4 l0 = ((const float4*)(lenght + (long long)e * 8))[0];
    const float4 l1 = ((const float4*)(lenght + (long long)e * 8))[1];
    len[0]=l0.x; len[1]=l0.y; len[2]=l0.z; len[3]=l0.w;
    len[4]=l1.x; len[5]=l1.y; len[6]=l1.z; len[7]=l1.w;

    float h0[6], h1[6], h2[6];
    #pragma unroll
    for (int j = 0; j < 6; ++j) {
        float a = 0.f;
        #pragma unroll
        for (int k = 0; k < 8; ++k) a += len[k] * sw0[k * 6 + j];
        a *= inv8;
        h0[j] = a / (1.f + __expf(-a));
    }
    #pragma unroll
    for (int j = 0; j < 6; ++j) {
        float a = 0.f;
        #pragma unroll
        for (int k = 0; k < 6; ++k) a += h0[k] * sw1[k * 6 + j];
        a *= inv6;
        h1[j] = a / (1.f + __expf(-a));
    }
    #pragma unroll
    for (int j = 0; j < 6; ++j) {
        float a = 0.f;
        #pragma unroll
        for (int k = 0; k < 6; ++k) a += h1[k] * sw2[k * 6 + j];
        a *= inv6;
        h2[j] = a * inv6 / (1.f + __expf(-a));   // fold final-layer 1/sqrt(6)
    }

    const float* ea = s_ea + threadIdx.x * 9;
    float y[9];
    #pragma unroll
    for (int i = 0; i < 9; ++i) y[i] = ea[i];

    const int snd = edge_index[e];
    const int r   = edge_index[N_EDGES + e];
    const int p   = offset[r] + rank[e];      // no atomic

    float4* rp = rec + (long long)p * 4;
    rp[0] = make_float4(h2[0], h2[1], h2[2], h2[3]);
    rp[1] = make_float4(h2[4], h2[5], y[0], y[1]);
    rp[2] = make_float4(y[2], y[3], y[4], y[5]);
    rp[3] = make_float4(y[6], y[7], y[8], __int_as_float(snd));
}

// ---------------------------------------------------------------------------
// K4: gather + message + segment-sum + node linear. One 64-lane wave / node.
// THIS ROUND: 128-thread blocks (2 waves, 2 nodes), 25000 blocks; NO LDS
// weight staging and NO __syncthreads anywhere — lw read directly from
// global (12 KB, hot in L2, broadcast 128-B wave reads). LDS is only the
// per-wave 1.5 KB m/row staging buffer with wave-internal lgkm fences.
// Rationale: static occupancy limits allowed 100% yet measured occ was 37%;
// suspect per-block prologue+barrier and 4-wave straggler holding. Finer
// blocks + zero block-coupling tests that theory directly.
// Inner loop unchanged (proven): 4 edges/phase ping-pong A/B, zero-pad
// overshoot, LDS-broadcast epilogue, coalesced row store.
// ---------------------------------------------------------------------------
#define EDGE_ACC(Ra,Rb,Rc,Rd,xx) do {                                          \
    const float w0c_ = Ra.x*f3a[0] + Ra.y*f3a[1] + Ra.z*f3a[2]                 \
                     + Ra.w*f3a[3] + Rb.x*f3a[4] + Rb.y*f3a[5];                \
    const float w1c_ = Ra.x*f3b[0] + Ra.y*f3b[1] + Ra.z*f3b[2]                 \
                     + Ra.w*f3b[3] + Rb.x*f3b[4] + Rb.y*f3b[5];                \
    const float w2c_ = Ra.x*f3c[0] + Ra.y*f3c[1] + Ra.z*f3c[2]                 \
                     + Ra.w*f3c[3] + Rb.x*f3c[4] + Rb.y*f3c[5];                \
    acc[0] += (w0c_ * (xx)) * Rb.z;                                            \
    const float a1_ = w1c_ * (xx);                                             \
    acc[1] += a1_ * Rb.w; acc[2] += a1_ * Rc.x; acc[3] += a1_ * Rc.y;          \
    const float a2_ = w2c_ * (xx);                                             \
    acc[4] += a2_ * Rc.z; acc[5] += a2_ * Rc.w;                                \
    acc[6] += a2_ * Rd.x; acc[7] += a2_ * Rd.y; acc[8] += a2_ * Rd.z;          \
} while (0)

__global__ __launch_bounds__(128) void gather_kernel(
    const float4* __restrict__ rec,          // (E+pad, 4 x float4) CSR order
    const float*  __restrict__ node_features,// (N, 32)
    const int*    __restrict__ offset,       // (N)
    const int*    __restrict__ deg,          // (N)
    const float*  __restrict__ fw3,          // (6, 96)
    const float*  __restrict__ lw0,          // (32, 32)
    const float*  __restrict__ lw1,          // (32, 32)
    const float*  __restrict__ lw2,          // (32, 32)
    float*        __restrict__ out)          // (N, 288)
{
    __shared__ float s_m[2][384];            // per-wave: m-stage then row-stage

    const int wave = threadIdx.x >> 6;
    const int l    = threadIdx.x & 63;
    const int c    = l & 31;
    const int h    = l >> 5;
    const int node = blockIdx.x * 2 + wave;     // 25000 blocks exact

    float f3a[6], f3b[6], f3c[6];
    #pragma unroll
    for (int k = 0; k < 6; ++k) {
        f3a[k] = fw3[k * 96 + c];
        f3b[k] = fw3[k * 96 + 32 + c];
        f3c[k] = fw3[k * 96 + 64 + c];
    }

    int off = offset[node];
    int dg  = deg[node];
    off = __builtin_amdgcn_readfirstlane(off);   // wave-uniform -> SGPR
    dg  = __builtin_amdgcn_readfirstlane(dg);
    const int nph = (dg + 3) >> 2;               // phases (4 slots each)

    const float4* rb = rec + (size_t)off * 4;    // SGPR base

    float acc[9] = {0.f,0.f,0.f,0.f,0.f,0.f,0.f,0.f,0.f};

    if (nph > 0) {
        // slot pairs: A handles {jA, jA+1}, B handles {jB, jB+1}
        int jA = 2 * h;
        int jB = 2 * h + 4;

        // prologue: load both pairs, x for A pair
        float4 A0 = rb[4*jA+0], A1 = rb[4*jA+1], A2 = rb[4*jA+2], A3 = rb[4*jA+3];
        float4 A4 = rb[4*jA+4], A5 = rb[4*jA+5], A6 = rb[4*jA+6], A7 = rb[4*jA+7];
        float4 B0 = rb[4*jB+0], B1 = rb[4*jB+1], B2 = rb[4*jB+2], B3 = rb[4*jB+3];
        float4 B4 = rb[4*jB+4], B5 = rb[4*jB+5], B6 = rb[4*jB+6], B7 = rb[4*jB+7];
        float xAr0 = node_features[(size_t)__float_as_int(A3.w) * CCH + c];
        float xAr1 = node_features[(size_t)__float_as_int(A7.w) * CCH + c];
        bool  vA0 = (jA < dg), vA1 = (jA + 1 < dg);
        float xBr0 = 0.f, xBr1 = 0.f;
        bool  vB0 = false, vB1 = false;

        int p = 0;
        while (true) {
            // ---- phase A: compute pair A; issue x for B; prefetch next A ----
            {
                const float xA0 = vA0 ? xAr0 : 0.f;
                const float xA1 = vA1 ? xAr1 : 0.f;
                EDGE_ACC(A0, A1, A2, A3, xA0);
                EDGE_ACC(A4, A5, A6, A7, xA1);
                xBr0 = node_features[(size_t)__float_as_int(B3.w) * CCH + c];
                xBr1 = node_features[(size_t)__float_as_int(B7.w) * CCH + c];
                vB0 = (jB < dg); vB1 = (jB + 1 < dg);
                jA += 8;
                A0 = rb[4*jA+0]; A1 = rb[4*jA+1]; A2 = rb[4*jA+2]; A3 = rb[4*jA+3];
                A4 = rb[4*jA+4]; A5 = rb[4*jA+5]; A6 = rb[4*jA+6]; A7 = rb[4*jA+7];
                if (++p == nph) break;
            }
            // ---- phase B: compute pair B; issue x for A; prefetch next B ----
            {
                const float xB0 = vB0 ? xBr0 : 0.f;
                const float xB1 = vB1 ? xBr1 : 0.f;
                EDGE_ACC(B0, B1, B2, B3, xB0);
                EDGE_ACC(B4, B5, B6, B7, xB1);
                xAr0 = node_features[(size_t)__float_as_int(A3.w) * CCH + c];
                xAr1 = node_features[(size_t)__float_as_int(A7.w) * CCH + c];
                vA0 = (jA < dg); vA1 = (jA + 1 < dg);
                jB += 8;
                B0 = rb[4*jB+0]; B1 = rb[4*jB+1]; B2 = rb[4*jB+2]; B3 = rb[4*jB+3];
                B4 = rb[4*jB+4]; B5 = rb[4*jB+5]; B6 = rb[4*jB+6]; B7 = rb[4*jB+7];
                if (++p == nph) break;
            }
        }
    }

    // fold halves: lanes 0..31 hold msg[c][0..8]
    #pragma unroll
    for (int k = 0; k < 9; ++k) acc[k] += __shfl_down(acc[k], 32);

    // stage msg into LDS: s_m[wave][c*12 + k]  (48-B stride, b128-aligned)
    if (h == 0) {
        float4* mp = (float4*)&s_m[wave][c * 12];
        mp[0] = make_float4(acc[0], acc[1], acc[2], acc[3]);
        mp[1] = make_float4(acc[4], acc[5], acc[6], acc[7]);
        s_m[wave][c * 12 + 8] = acc[8];
    }
    asm volatile("s_waitcnt lgkmcnt(0)" ::: "memory");   // wave-internal fence

    // node linear: broadcast-read m from LDS, lw direct from global (L2-hot);
    // halves split the cc loop
    const int d = c;
    float o0 = 0.f;
    float o1[3] = {0.f, 0.f, 0.f};
    float o2[5] = {0.f, 0.f, 0.f, 0.f, 0.f};
    for (int cc = h * 16; cc < h * 16 + 16; ++cc) {
        const float4 ma = *(const float4*)&s_m[wave][cc * 12];
        const float4 mb = *(const float4*)&s_m[wave][cc * 12 + 4];
        const float  m8 = s_m[wave][cc * 12 + 8];
        o0 += ma.x * lw0[cc * 32 + d];
        const float w1 = lw1[cc * 32 + d];
        o1[0] += ma.y * w1; o1[1] += ma.z * w1; o1[2] += ma.w * w1;
        const float w2 = lw2[cc * 32 + d];
        o2[0] += mb.x * w2; o2[1] += mb.y * w2; o2[2] += mb.z * w2;
        o2[3] += mb.w * w2; o2[4] += m8   * w2;
    }

    o0 += __shfl_down(o0, 32);
    #pragma unroll
    for (int i = 0; i < 3; ++i) o1[i] += __shfl_down(o1[i], 32);
    #pragma unroll
    for (int i = 0; i < 5; ++i) o2[i] += __shfl_down(o2[i], 32);

    // stage the 288-float output row in LDS (reuse s_m), store coalesced
    if (h == 0) {
        const float inv32 = 0.17677669529663687f;  // 1/sqrt(32)
        float* rw = &s_m[wave][0];
        rw[d] = o0 * inv32;
        #pragma unroll
        for (int i = 0; i < 3; ++i) rw[32 + d * 3 + i] = o1[i] * inv32;
        #pragma unroll
        for (int i = 0; i < 5; ++i) rw[128 + d * 5 + i] = o2[i] * inv32;
    }
    asm volatile("s_waitcnt lgkmcnt(0)" ::: "memory");

    const float4* rowp = (const float4*)&s_m[wave][0];
    float4* op4 = (float4*)(out + (size_t)node * ROW);
    op4[l] = rowp[l];
    if (l < 8) op4[64 + l] = rowp[64 + l];
}

extern "C" void kernel_launch(void* const* d_in, const int* in_sizes, int n_in,
                              void* d_out, int out_size, void* d_ws, size_t ws_size,
                              hipStream_t stream)
{
    const float* lenght = (const float*)d_in[0];
    const float* nf     = (const float*)d_in[1];
    const float* ea     = (const float*)d_in[2];
    const int*   ei     = (const int*)d_in[3];
    const float* fw0    = (const float*)d_in[4];
    const float* fw1    = (const float*)d_in[5];
    const float* fw2    = (const float*)d_in[6];
    const float* fw3    = (const float*)d_in[7];
    const float* lw0    = (const float*)d_in[8];
    const float* lw1    = (const float*)d_in[9];
    const float* lw2    = (const float*)d_in[10];
    float* out = (float*)d_out;

    // workspace layout
    char* ws = (char*)d_ws;
    float4* rec    = (float4*)ws; ws += ((size_t)N_EDGES * 4 + REC_PAD) * sizeof(float4);
    int* rank      = (int*)ws;    ws += (size_t)N_EDGES * sizeof(int);
    int* deg       = (int*)ws;    ws += (size_t)N_NODES * sizeof(int);
    int* offset    = (int*)ws;    ws += (size_t)N_NODES * sizeof(int);
    int* lexcl     = (int*)ws;    ws += (size_t)N_NODES * sizeof(int);
    int* blocksum  = (int*)ws;    ws += (size_t)SCAN_BLOCKS * sizeof(int);
    int* blockpref = (int*)ws;    ws += (size_t)SCAN_BLOCKS * sizeof(int);
    float4* recpad = rec + (size_t)N_EDGES * 4;

    hipMemsetAsync(deg, 0, (size_t)N_NODES * sizeof(int), stream);
    hipMemsetAsync(recpad, 0, (size_t)REC_PAD * sizeof(float4), stream);

    const int EB = (N_EDGES + 255) / 256;
    rank_kernel        <<<EB, 256, 0, stream>>>(ei, deg, rank);
    scan_local_kernel  <<<SCAN_BLOCKS, 256, 0, stream>>>(deg, lexcl, blocksum);
    scan_top_kernel    <<<1, 256, 0, stream>>>(blocksum, blockpref);
    scan_addback_kernel<<<SCAN_BLOCKS, 256, 0, stream>>>(lexcl, blockpref, offset);
    pack_kernel        <<<EB, 256, 0, stream>>>(lenght, ea, ei, fw0, fw1, fw2,
                                                offset, rank, rec);
    gather_kernel      <<<N_NODES / 2, 128, 0, stream>>>(
        rec, nf, offset, deg, fw3, lw0, lw1, lw2, out);
}